// Round 1
// baseline (1807.800 us; speedup 1.0000x reference)
//
#include <hip/hip_runtime.h>
#include <math.h>

// Problem constants
#define Bdim 32
#define Ndim 2048
#define Cdim 3
#define Kdim 20
#define Edim 64
#define NPART 27                 // 6 first moments + 21 second moments
#define NBLK1 4096               // k1 grid = 128 x 32
#define CNT (Bdim * Ndim * Kdim) // BN sample count = 1,310,720

// ---------------------------------------------------------------------------
// Kernel 1: KNN top-20 per point + 27 edge-moment partial sums per block.
// One wave (64 lanes) per point; 32 candidates per lane in registers as
// sortable u64 keys (pdist in high 32 bits, 2047-j in low bits -> max-reduce
// == argmax with lower-index tie-break, keys globally unique).
// ---------------------------------------------------------------------------
__global__ __launch_bounds__(256) void k1_knn_stats(
    const float* __restrict__ xyz, int* __restrict__ idx_out,
    float* __restrict__ partials) {
  __shared__ float4 pts[Ndim];       // {x, y, z, ||p||^2}  (32 KiB)
  __shared__ float red[4][NPART];

  const int b = blockIdx.y;
  const int tid = threadIdx.x;
  const float* xb = xyz + (size_t)b * Ndim * Cdim;

  // Stage xyz[b] into LDS (coalesced global reads, scattered LDS writes)
  float* sp = (float*)&pts[0];
  for (int g = tid; g < Ndim * Cdim; g += 256) {
    sp[(g / 3) * 4 + (g % 3)] = xb[g];
  }
  __syncthreads();
  for (int p = tid; p < Ndim; p += 256) {
    float4 q = pts[p];
    pts[p].w = q.x * q.x + q.y * q.y + q.z * q.z;
  }
  __syncthreads();

  const int w = tid >> 6;
  const int lane = tid & 63;

  float acc[NPART];
#pragma unroll
  for (int c = 0; c < NPART; ++c) acc[c] = 0.0f;

  for (int s = 0; s < 4; ++s) {
    const int i = blockIdx.x * 16 + w * 4 + s;
    const float4 pi = pts[i];

    unsigned long long keys[32];
#pragma unroll
    for (int t = 0; t < 32; ++t) {
      const int j = t * 64 + lane;
      const float4 pj = pts[j];
      const float dot = pi.x * pj.x + pi.y * pj.y + pi.z * pj.z;
      const float pd = 2.0f * dot - pi.w - pj.w;   // -||pi-pj||^2
      unsigned u = __float_as_uint(pd);
      u = (u & 0x80000000u) ? ~u : (u | 0x80000000u);  // sortable ascending
      keys[t] = ((unsigned long long)u << 32) | (unsigned)(2047 - j);
    }

    int myJ = 0;
    for (int r = 0; r < Kdim; ++r) {
      unsigned long long best = keys[0];
#pragma unroll
      for (int t = 1; t < 32; ++t) best = (keys[t] > best) ? keys[t] : best;
#pragma unroll
      for (int d = 1; d < 64; d <<= 1) {
        unsigned long long o = __shfl_xor(best, d, 64);
        best = (o > best) ? o : best;
      }
      const int j = 2047 - (int)(best & 0x7FFull);
      if (lane == r) myJ = j;
      // keys are unique -> exact-match zap hits only the winner, all lanes run it
#pragma unroll
      for (int t = 0; t < 32; ++t)
        if (keys[t] == best) keys[t] = 0ull;
    }

    if (lane < Kdim) {
      idx_out[((size_t)b * Ndim + i) * Kdim + lane] = myJ;
      const float4 pj = pts[myJ];
      float ev[6];
      ev[0] = pi.x; ev[1] = pi.y; ev[2] = pi.z;
      ev[3] = pj.x - pi.x; ev[4] = pj.y - pi.y; ev[5] = pj.z - pi.z;
#pragma unroll
      for (int a = 0; a < 6; ++a) acc[a] += ev[a];
      int c = 6;
#pragma unroll
      for (int a = 0; a < 6; ++a)
#pragma unroll
        for (int d = a; d < 6; ++d) { acc[c] += ev[a] * ev[d]; ++c; }
    }
  }

  // Block reduction of the 27 accumulators
#pragma unroll
  for (int c = 0; c < NPART; ++c) {
    float v = acc[c];
#pragma unroll
    for (int d = 1; d < 64; d <<= 1) v += __shfl_xor(v, d, 64);
    if (lane == 0) red[w][c] = v;
  }
  __syncthreads();
  if (tid < NPART) {
    const int bid = blockIdx.y * gridDim.x + blockIdx.x;
    partials[(size_t)bid * NPART + tid] =
        red[0][tid] + red[1][tid] + red[2][tid] + red[3][tid];
  }
}

// ---------------------------------------------------------------------------
// Kernel 2: reduce 4096 partials (f64), fold 6x6 moments through W into
// per-channel BN scale/shift.  scale_e = gamma*rstd ; shift_e = beta - mean*scale.
// ---------------------------------------------------------------------------
__global__ __launch_bounds__(256) void k2_bnstats(
    const float* __restrict__ partials, const float* __restrict__ W,
    const float* __restrict__ gamma, const float* __restrict__ beta,
    float* __restrict__ ss) {
  __shared__ double stat[NPART];
  __shared__ double red[4];
  const int tid = threadIdx.x;
  const int lane = tid & 63;
  const int w = tid >> 6;

  for (int c = 0; c < NPART; ++c) {
    double v = 0.0;
    for (int p = tid; p < NBLK1; p += 256) v += (double)partials[(size_t)p * NPART + c];
#pragma unroll
    for (int d = 1; d < 64; d <<= 1) v += __shfl_xor(v, d, 64);
    if (lane == 0) red[w] = v;
    __syncthreads();
    if (tid == 0) stat[c] = red[0] + red[1] + red[2] + red[3];
    __syncthreads();
  }

  if (tid < Edim) {
    const double inv = 1.0 / (double)CNT;
    double mu[6];
#pragma unroll
    for (int c = 0; c < 6; ++c) mu[c] = stat[c] * inv;
    double wv[6];
#pragma unroll
    for (int c = 0; c < 6; ++c) wv[c] = (double)W[tid * 6 + c];
    double m = 0.0;
#pragma unroll
    for (int c = 0; c < 6; ++c) m += wv[c] * mu[c];
    double q = 0.0;
    int s = 6;
#pragma unroll
    for (int a = 0; a < 6; ++a)
#pragma unroll
      for (int d = a; d < 6; ++d) {
        q += (a == d ? 1.0 : 2.0) * wv[a] * wv[d] * (stat[s] * inv);
        ++s;
      }
    const double var = q - m * m;
    const double rstd = 1.0 / sqrt(var + 1e-5);
    const float scale = (float)((double)gamma[tid] * rstd);
    const float shift = (float)((double)beta[tid] - m * rstd * (double)gamma[tid]);
    ss[tid] = scale;
    ss[Edim + tid] = shift;
  }
}

// ---------------------------------------------------------------------------
// Kernel 3: recompute h per (b,n,k,e), BN + hardswish, max over k, write
// out[b,e,n] coalesced via LDS transpose.  lane = channel e; wave = point.
// ---------------------------------------------------------------------------
__global__ __launch_bounds__(256) void k3_out(
    const float* __restrict__ xyz, const int* __restrict__ idx,
    const float* __restrict__ W, const float* __restrict__ ss,
    float* __restrict__ out) {
  __shared__ float sm[64][65];
  const int b = blockIdx.y;
  const int n0 = blockIdx.x * 64;
  const int tid = threadIdx.x;
  const int w = tid >> 6;
  const int lane = tid & 63;

  float wv[6];
#pragma unroll
  for (int c = 0; c < 6; ++c) wv[c] = W[lane * 6 + c];
  const float scale = ss[lane];
  const float shift = ss[Edim + lane];
  const float* xb = xyz + (size_t)b * Ndim * Cdim;

  for (int s = 0; s < 16; ++s) {
    const int i = n0 + w * 16 + s;
    const float xi0 = xb[i * 3], xi1 = xb[i * 3 + 1], xi2 = xb[i * 3 + 2];
    const float hbase = wv[0] * xi0 + wv[1] * xi1 + wv[2] * xi2;
    const int* ip = idx + ((size_t)b * Ndim + i) * Kdim;
    float m = -INFINITY;
    for (int k = 0; k < Kdim; ++k) {
      const int j = ip[k];
      const float d0 = xb[j * 3] - xi0;
      const float d1 = xb[j * 3 + 1] - xi1;
      const float d2 = xb[j * 3 + 2] - xi2;
      const float h = hbase + wv[3] * d0 + wv[4] * d1 + wv[5] * d2;
      const float a = h * scale + shift;
      const float r6 = fminf(fmaxf(a + 3.0f, 0.0f), 6.0f);
      const float hs = a * r6 * (1.0f / 6.0f);
      m = fmaxf(m, hs);
    }
    sm[w * 16 + s][lane] = m;
  }
  __syncthreads();

#pragma unroll
  for (int r = 0; r < 16; ++r) {
    const int e = r * 4 + w;
    out[((size_t)b * Edim + e) * Ndim + n0 + lane] = sm[lane][e];
  }
}

// ---------------------------------------------------------------------------
extern "C" void kernel_launch(void* const* d_in, const int* in_sizes, int n_in,
                              void* d_out, int out_size, void* d_ws, size_t ws_size,
                              hipStream_t stream) {
  const float* xyz = (const float*)d_in[0];
  const float* W = (const float*)d_in[1];
  const float* gamma = (const float*)d_in[2];
  const float* beta = (const float*)d_in[3];
  float* out = (float*)d_out;

  char* ws = (char*)d_ws;
  int* idx = (int*)ws;                                        // 5,242,880 B
  float* partials = (float*)(ws + (size_t)Bdim * Ndim * Kdim * 4);  // 442,368 B
  float* ss = (float*)(ws + (size_t)Bdim * Ndim * Kdim * 4 + (size_t)NBLK1 * NPART * 4);

  // Output 0: xyz passthrough
  hipMemcpyAsync(out, xyz, (size_t)Bdim * Ndim * Cdim * sizeof(float),
                 hipMemcpyDeviceToDevice, stream);

  k1_knn_stats<<<dim3(Ndim / 16, Bdim), 256, 0, stream>>>(xyz, idx, partials);
  k2_bnstats<<<1, 256, 0, stream>>>(partials, W, gamma, beta, ss);
  k3_out<<<dim3(Ndim / 64, Bdim), 256, 0, stream>>>(
      xyz, idx, W, ss, out + (size_t)Bdim * Ndim * Cdim);
}

// Round 2
// 1064.931 us; speedup vs baseline: 1.6976x; 1.6976x over previous
//
#include <hip/hip_runtime.h>
#include <math.h>

// Problem constants
#define Bdim 32
#define Ndim 2048
#define Cdim 3
#define Kdim 20
#define Edim 64
#define NPART 27                 // 6 first moments + 21 second moments
#define NBLK1 4096               // k1 grid = 128 x 32
#define CNT (Bdim * Ndim * Kdim) // BN sample count = 1,310,720

// ---------------------------------------------------------------------------
// Kernel 1: KNN top-20 per point + 27 edge-moment partial sums per block.
// One wave per point; 32 u32 sortable keys per lane in registers. Per-lane
// cached top-2 (head/second) -> per round only a 64-lane butterfly max on the
// composite (key, 2047-j) u64 + winner pop. Full rescan only on a lane's 2nd+
// win (rare). Zap of the consumed slot is done via a wave-uniform slot index
// (readfirstlane -> scalar switch), so it costs SALU, not a 32-op VALU scan.
// ---------------------------------------------------------------------------
__global__ __launch_bounds__(256, 4) void k1_knn_stats(
    const float* __restrict__ xyz, int* __restrict__ idx_out,
    float* __restrict__ partials) {
  __shared__ float4 pts[Ndim];       // {x, y, z, ||p||^2}  (32 KiB)
  __shared__ float red[4][NPART];

  const int b = blockIdx.y;
  const int tid = threadIdx.x;
  const float* xb = xyz + (size_t)b * Ndim * Cdim;

  // Stage xyz[b] into LDS
  float* sp = (float*)&pts[0];
  for (int g = tid; g < Ndim * Cdim; g += 256) {
    sp[(g / 3) * 4 + (g % 3)] = xb[g];
  }
  __syncthreads();
  for (int p = tid; p < Ndim; p += 256) {
    float4 q = pts[p];
    pts[p].w = q.x * q.x + q.y * q.y + q.z * q.z;
  }
  __syncthreads();

  const int w = tid >> 6;
  const int lane = tid & 63;
  const unsigned il = 2047u - (unsigned)lane;

  float acc[NPART];
#pragma unroll
  for (int c = 0; c < NPART; ++c) acc[c] = 0.0f;

  for (int s = 0; s < 4; ++s) {
    const int i = blockIdx.x * 16 + w * 4 + s;
    const float4 pi = pts[i];

    unsigned kd[32];
    unsigned hk = 0u, hlo = 0u;   // head: key + (2047-j)
    unsigned sk = 0u, slo = 0u;   // second: key + (2047-j); sk==0 -> invalid

#pragma unroll
    for (int t = 0; t < 32; ++t) {
      const int j = t * 64 + lane;
      const float4 pj = pts[j];
      const float dot = pi.x * pj.x + pi.y * pj.y + pi.z * pj.z;
      const float pd = 2.0f * dot - pi.w - pj.w;   // -||pi-pj||^2  (same arith as R1)
      const unsigned u = __float_as_uint(pd);
      const unsigned k = u ^ ((unsigned)(((int)u) >> 31) | 0x80000000u); // sortable, >0 always
      kd[t] = k;
      const unsigned tlo = il - (unsigned)(t * 64);
      const bool b1 = k > hk;
      const bool b2 = k > sk;
      sk  = b1 ? hk  : (b2 ? k   : sk);
      slo = b1 ? hlo : (b2 ? tlo : slo);
      hk  = b1 ? k   : hk;
      hlo = b1 ? tlo : hlo;
    }

    unsigned myJ = 0u;
    for (int r = 0; r < Kdim; ++r) {
      const unsigned long long H = ((unsigned long long)hk << 32) | hlo;
      unsigned long long best = H;
#pragma unroll
      for (int d = 1; d < 64; d <<= 1) {
        const unsigned long long o = __shfl_xor(best, d, 64);
        best = (o > best) ? o : best;
      }
      const unsigned jwin = 2047u - ((unsigned)best & 0x7FFu);
      if (lane == r) myJ = jwin;

      // Zap consumed slot: slot index is wave-uniform -> scalar switch
      const unsigned zs = (unsigned)__builtin_amdgcn_readfirstlane((int)(jwin >> 6));
      const bool zl = ((unsigned)lane == (jwin & 63u));
      switch (zs) {
#define ZAP(T) case T: if (zl) kd[T] = 0u; break;
        ZAP(0) ZAP(1) ZAP(2) ZAP(3) ZAP(4) ZAP(5) ZAP(6) ZAP(7)
        ZAP(8) ZAP(9) ZAP(10) ZAP(11) ZAP(12) ZAP(13) ZAP(14) ZAP(15)
        ZAP(16) ZAP(17) ZAP(18) ZAP(19) ZAP(20) ZAP(21) ZAP(22) ZAP(23)
        ZAP(24) ZAP(25) ZAP(26) ZAP(27) ZAP(28) ZAP(29) ZAP(30) ZAP(31)
#undef ZAP
        default: break;
      }

      // Winner pops: promote second, or rescan (rare: lane's 2nd+ win)
      if (H == best) {
        if (sk != 0u) {
          hk = sk; hlo = slo; sk = 0u;
        } else {
          unsigned bk = 0u, bs = 0u;
#pragma unroll
          for (int t = 0; t < 32; ++t) {
            const bool bb = kd[t] > bk;
            bk = bb ? kd[t] : bk;
            bs = bb ? (unsigned)t : bs;
          }
          hk = bk; hlo = il - (bs << 6);
        }
      }
    }

    if (lane < Kdim) {
      idx_out[((size_t)b * Ndim + i) * Kdim + lane] = (int)myJ;
      const float4 pj = pts[myJ];
      float ev[6];
      ev[0] = pi.x; ev[1] = pi.y; ev[2] = pi.z;
      ev[3] = pj.x - pi.x; ev[4] = pj.y - pi.y; ev[5] = pj.z - pi.z;
#pragma unroll
      for (int a = 0; a < 6; ++a) acc[a] += ev[a];
      int c = 6;
#pragma unroll
      for (int a = 0; a < 6; ++a)
#pragma unroll
        for (int d = a; d < 6; ++d) { acc[c] += ev[a] * ev[d]; ++c; }
    }
  }

  // Block reduction of the 27 accumulators
#pragma unroll
  for (int c = 0; c < NPART; ++c) {
    float v = acc[c];
#pragma unroll
    for (int d = 1; d < 64; d <<= 1) v += __shfl_xor(v, d, 64);
    if (lane == 0) red[w][c] = v;
  }
  __syncthreads();
  if (tid < NPART) {
    const int bid = blockIdx.y * gridDim.x + blockIdx.x;
    partials[(size_t)bid * NPART + tid] =
        red[0][tid] + red[1][tid] + red[2][tid] + red[3][tid];
  }
}

// ---------------------------------------------------------------------------
// Kernel 2: reduce 4096 partials (f64), fold 6x6 moments through W into
// per-channel BN scale/shift.
// ---------------------------------------------------------------------------
__global__ __launch_bounds__(256) void k2_bnstats(
    const float* __restrict__ partials, const float* __restrict__ W,
    const float* __restrict__ gamma, const float* __restrict__ beta,
    float* __restrict__ ss) {
  __shared__ double stat[NPART];
  __shared__ double red[4];
  const int tid = threadIdx.x;
  const int lane = tid & 63;
  const int w = tid >> 6;

  for (int c = 0; c < NPART; ++c) {
    double v = 0.0;
    for (int p = tid; p < NBLK1; p += 256) v += (double)partials[(size_t)p * NPART + c];
#pragma unroll
    for (int d = 1; d < 64; d <<= 1) v += __shfl_xor(v, d, 64);
    if (lane == 0) red[w] = v;
    __syncthreads();
    if (tid == 0) stat[c] = red[0] + red[1] + red[2] + red[3];
    __syncthreads();
  }

  if (tid < Edim) {
    const double inv = 1.0 / (double)CNT;
    double mu[6];
#pragma unroll
    for (int c = 0; c < 6; ++c) mu[c] = stat[c] * inv;
    double wv[6];
#pragma unroll
    for (int c = 0; c < 6; ++c) wv[c] = (double)W[tid * 6 + c];
    double m = 0.0;
#pragma unroll
    for (int c = 0; c < 6; ++c) m += wv[c] * mu[c];
    double q = 0.0;
    int s = 6;
#pragma unroll
    for (int a = 0; a < 6; ++a)
#pragma unroll
      for (int d = a; d < 6; ++d) {
        q += (a == d ? 1.0 : 2.0) * wv[a] * wv[d] * (stat[s] * inv);
        ++s;
      }
    const double var = q - m * m;
    const double rstd = 1.0 / sqrt(var + 1e-5);
    const float scale = (float)((double)gamma[tid] * rstd);
    const float shift = (float)((double)beta[tid] - m * rstd * (double)gamma[tid]);
    ss[tid] = scale;
    ss[Edim + tid] = shift;
  }
}

// ---------------------------------------------------------------------------
// Kernel 3: recompute h per (b,n,k,e), BN + hardswish, max over k, write
// out[b,e,n] coalesced via LDS transpose.  lane = channel e; wave = point.
// ---------------------------------------------------------------------------
__global__ __launch_bounds__(256) void k3_out(
    const float* __restrict__ xyz, const int* __restrict__ idx,
    const float* __restrict__ W, const float* __restrict__ ss,
    float* __restrict__ out) {
  __shared__ float sm[64][65];
  const int b = blockIdx.y;
  const int n0 = blockIdx.x * 64;
  const int tid = threadIdx.x;
  const int w = tid >> 6;
  const int lane = tid & 63;

  float wv[6];
#pragma unroll
  for (int c = 0; c < 6; ++c) wv[c] = W[lane * 6 + c];
  const float scale = ss[lane];
  const float shift = ss[Edim + lane];
  const float* xb = xyz + (size_t)b * Ndim * Cdim;

  for (int s = 0; s < 16; ++s) {
    const int i = n0 + w * 16 + s;
    const float xi0 = xb[i * 3], xi1 = xb[i * 3 + 1], xi2 = xb[i * 3 + 2];
    const float hbase = wv[0] * xi0 + wv[1] * xi1 + wv[2] * xi2;
    const int* ip = idx + ((size_t)b * Ndim + i) * Kdim;
    float m = -INFINITY;
    for (int k = 0; k < Kdim; ++k) {
      const int j = ip[k];
      const float d0 = xb[j * 3] - xi0;
      const float d1 = xb[j * 3 + 1] - xi1;
      const float d2 = xb[j * 3 + 2] - xi2;
      const float h = hbase + wv[3] * d0 + wv[4] * d1 + wv[5] * d2;
      const float a = h * scale + shift;
      const float r6 = fminf(fmaxf(a + 3.0f, 0.0f), 6.0f);
      const float hs = a * r6 * (1.0f / 6.0f);
      m = fmaxf(m, hs);
    }
    sm[w * 16 + s][lane] = m;
  }
  __syncthreads();

#pragma unroll
  for (int r = 0; r < 16; ++r) {
    const int e = r * 4 + w;
    out[((size_t)b * Edim + e) * Ndim + n0 + lane] = sm[lane][e];
  }
}

// ---------------------------------------------------------------------------
extern "C" void kernel_launch(void* const* d_in, const int* in_sizes, int n_in,
                              void* d_out, int out_size, void* d_ws, size_t ws_size,
                              hipStream_t stream) {
  const float* xyz = (const float*)d_in[0];
  const float* W = (const float*)d_in[1];
  const float* gamma = (const float*)d_in[2];
  const float* beta = (const float*)d_in[3];
  float* out = (float*)d_out;

  char* ws = (char*)d_ws;
  int* idx = (int*)ws;                                        // 5,242,880 B
  float* partials = (float*)(ws + (size_t)Bdim * Ndim * Kdim * 4);  // 442,368 B
  float* ss = (float*)(ws + (size_t)Bdim * Ndim * Kdim * 4 + (size_t)NBLK1 * NPART * 4);

  // Output 0: xyz passthrough
  hipMemcpyAsync(out, xyz, (size_t)Bdim * Ndim * Cdim * sizeof(float),
                 hipMemcpyDeviceToDevice, stream);

  k1_knn_stats<<<dim3(Ndim / 16, Bdim), 256, 0, stream>>>(xyz, idx, partials);
  k2_bnstats<<<1, 256, 0, stream>>>(partials, W, gamma, beta, ss);
  k3_out<<<dim3(Ndim / 64, Bdim), 256, 0, stream>>>(
      xyz, idx, W, ss, out + (size_t)Bdim * Ndim * Cdim);
}

// Round 3
// 776.543 us; speedup vs baseline: 2.3280x; 1.3714x over previous
//
#include <hip/hip_runtime.h>
#include <math.h>

// Problem constants
#define Bdim 32
#define Ndim 2048
#define Cdim 3
#define Kdim 20
#define Edim 64
#define NPART 27                 // 6 first moments + 21 second moments
#define NBLK1 4096               // k1 grid = 128 x 32
#define CNT (Bdim * Ndim * Kdim) // BN sample count = 1,310,720

// ---------------------------------------------------------------------------
// Kernel 1: KNN top-20 per point + 27 edge-moment partial sums per block.
// One wave per point; 32 u32 sortable keys per lane in registers. Per-lane
// cached top-2 (head/second) -> per round only a 64-lane butterfly max on the
// composite (key, 2047-j) u64 + winner pop. Full rescan only on a lane's 2nd+
// win (rare). Zap of the consumed slot via wave-uniform slot index
// (readfirstlane -> scalar switch): SALU, not a 32-op VALU scan.
// NOTE: min-waves hint must stay <=2 — at 4 the allocator caps VGPRs at 64,
// kd[32] spills to scratch, and the kernel becomes spill-BW-bound (R2: 915 MB
// WRITE_SIZE, VALUBusy 2.3%).
// ---------------------------------------------------------------------------
__global__ __launch_bounds__(256, 2) void k1_knn_stats(
    const float* __restrict__ xyz, int* __restrict__ idx_out,
    float* __restrict__ partials) {
  __shared__ float4 pts[Ndim];       // {x, y, z, ||p||^2}  (32 KiB)
  __shared__ float red[4][NPART];

  const int b = blockIdx.y;
  const int tid = threadIdx.x;
  const float* xb = xyz + (size_t)b * Ndim * Cdim;

  // Stage xyz[b] into LDS
  float* sp = (float*)&pts[0];
  for (int g = tid; g < Ndim * Cdim; g += 256) {
    sp[(g / 3) * 4 + (g % 3)] = xb[g];
  }
  __syncthreads();
  for (int p = tid; p < Ndim; p += 256) {
    float4 q = pts[p];
    pts[p].w = q.x * q.x + q.y * q.y + q.z * q.z;
  }
  __syncthreads();

  const int w = tid >> 6;
  const int lane = tid & 63;
  const unsigned il = 2047u - (unsigned)lane;

  float acc[NPART];
#pragma unroll
  for (int c = 0; c < NPART; ++c) acc[c] = 0.0f;

  for (int s = 0; s < 4; ++s) {
    const int i = blockIdx.x * 16 + w * 4 + s;
    const float4 pi = pts[i];

    unsigned kd[32];
    unsigned hk = 0u, hlo = 0u;   // head: key + (2047-j)
    unsigned sk = 0u, slo = 0u;   // second: key + (2047-j); sk==0 -> invalid

#pragma unroll
    for (int t = 0; t < 32; ++t) {
      const int j = t * 64 + lane;
      const float4 pj = pts[j];
      const float dot = pi.x * pj.x + pi.y * pj.y + pi.z * pj.z;
      const float pd = 2.0f * dot - pi.w - pj.w;   // -||pi-pj||^2  (same arith as R1)
      const unsigned u = __float_as_uint(pd);
      const unsigned k = u ^ ((unsigned)(((int)u) >> 31) | 0x80000000u); // sortable, >0 always
      kd[t] = k;
      const unsigned tlo = il - (unsigned)(t * 64);
      const bool b1 = k > hk;
      const bool b2 = k > sk;
      sk  = b1 ? hk  : (b2 ? k   : sk);
      slo = b1 ? hlo : (b2 ? tlo : slo);
      hk  = b1 ? k   : hk;
      hlo = b1 ? tlo : hlo;
    }

    unsigned myJ = 0u;
    for (int r = 0; r < Kdim; ++r) {
      const unsigned long long H = ((unsigned long long)hk << 32) | hlo;
      unsigned long long best = H;
#pragma unroll
      for (int d = 1; d < 64; d <<= 1) {
        const unsigned long long o = __shfl_xor(best, d, 64);
        best = (o > best) ? o : best;
      }
      const unsigned jwin = 2047u - ((unsigned)best & 0x7FFu);
      if (lane == r) myJ = jwin;

      // Zap consumed slot: slot index is wave-uniform -> scalar switch
      const unsigned zs = (unsigned)__builtin_amdgcn_readfirstlane((int)(jwin >> 6));
      const bool zl = ((unsigned)lane == (jwin & 63u));
      switch (zs) {
#define ZAP(T) case T: if (zl) kd[T] = 0u; break;
        ZAP(0) ZAP(1) ZAP(2) ZAP(3) ZAP(4) ZAP(5) ZAP(6) ZAP(7)
        ZAP(8) ZAP(9) ZAP(10) ZAP(11) ZAP(12) ZAP(13) ZAP(14) ZAP(15)
        ZAP(16) ZAP(17) ZAP(18) ZAP(19) ZAP(20) ZAP(21) ZAP(22) ZAP(23)
        ZAP(24) ZAP(25) ZAP(26) ZAP(27) ZAP(28) ZAP(29) ZAP(30) ZAP(31)
#undef ZAP
        default: break;
      }

      // Winner pops: promote second, or rescan (rare: lane's 2nd+ win)
      if (H == best) {
        if (sk != 0u) {
          hk = sk; hlo = slo; sk = 0u;
        } else {
          unsigned bk = 0u, bs = 0u;
#pragma unroll
          for (int t = 0; t < 32; ++t) {
            const bool bb = kd[t] > bk;
            bk = bb ? kd[t] : bk;
            bs = bb ? (unsigned)t : bs;
          }
          hk = bk; hlo = il - (bs << 6);
        }
      }
    }

    if (lane < Kdim) {
      idx_out[((size_t)b * Ndim + i) * Kdim + lane] = (int)myJ;
      const float4 pj = pts[myJ];
      float ev[6];
      ev[0] = pi.x; ev[1] = pi.y; ev[2] = pi.z;
      ev[3] = pj.x - pi.x; ev[4] = pj.y - pi.y; ev[5] = pj.z - pi.z;
#pragma unroll
      for (int a = 0; a < 6; ++a) acc[a] += ev[a];
      int c = 6;
#pragma unroll
      for (int a = 0; a < 6; ++a)
#pragma unroll
        for (int d = a; d < 6; ++d) { acc[c] += ev[a] * ev[d]; ++c; }
    }
  }

  // Block reduction of the 27 accumulators
#pragma unroll
  for (int c = 0; c < NPART; ++c) {
    float v = acc[c];
#pragma unroll
    for (int d = 1; d < 64; d <<= 1) v += __shfl_xor(v, d, 64);
    if (lane == 0) red[w][c] = v;
  }
  __syncthreads();
  if (tid < NPART) {
    const int bid = blockIdx.y * gridDim.x + blockIdx.x;
    partials[(size_t)bid * NPART + tid] =
        red[0][tid] + red[1][tid] + red[2][tid] + red[3][tid];
  }
}

// ---------------------------------------------------------------------------
// Kernel 2: reduce 4096 partials (f64), fold 6x6 moments through W into
// per-channel BN scale/shift.
// ---------------------------------------------------------------------------
__global__ __launch_bounds__(256) void k2_bnstats(
    const float* __restrict__ partials, const float* __restrict__ W,
    const float* __restrict__ gamma, const float* __restrict__ beta,
    float* __restrict__ ss) {
  __shared__ double stat[NPART];
  __shared__ double red[4];
  const int tid = threadIdx.x;
  const int lane = tid & 63;
  const int w = tid >> 6;

  for (int c = 0; c < NPART; ++c) {
    double v = 0.0;
    for (int p = tid; p < NBLK1; p += 256) v += (double)partials[(size_t)p * NPART + c];
#pragma unroll
    for (int d = 1; d < 64; d <<= 1) v += __shfl_xor(v, d, 64);
    if (lane == 0) red[w] = v;
    __syncthreads();
    if (tid == 0) stat[c] = red[0] + red[1] + red[2] + red[3];
    __syncthreads();
  }

  if (tid < Edim) {
    const double inv = 1.0 / (double)CNT;
    double mu[6];
#pragma unroll
    for (int c = 0; c < 6; ++c) mu[c] = stat[c] * inv;
    double wv[6];
#pragma unroll
    for (int c = 0; c < 6; ++c) wv[c] = (double)W[tid * 6 + c];
    double m = 0.0;
#pragma unroll
    for (int c = 0; c < 6; ++c) m += wv[c] * mu[c];
    double q = 0.0;
    int s = 6;
#pragma unroll
    for (int a = 0; a < 6; ++a)
#pragma unroll
      for (int d = a; d < 6; ++d) {
        q += (a == d ? 1.0 : 2.0) * wv[a] * wv[d] * (stat[s] * inv);
        ++s;
      }
    const double var = q - m * m;
    const double rstd = 1.0 / sqrt(var + 1e-5);
    const float scale = (float)((double)gamma[tid] * rstd);
    const float shift = (float)((double)beta[tid] - m * rstd * (double)gamma[tid]);
    ss[tid] = scale;
    ss[Edim + tid] = shift;
  }
}

// ---------------------------------------------------------------------------
// Kernel 3: recompute h per (b,n,k,e), BN + hardswish, max over k, write
// out[b,e,n] coalesced via LDS transpose.  lane = channel e; wave = point.
// ---------------------------------------------------------------------------
__global__ __launch_bounds__(256) void k3_out(
    const float* __restrict__ xyz, const int* __restrict__ idx,
    const float* __restrict__ W, const float* __restrict__ ss,
    float* __restrict__ out) {
  __shared__ float sm[64][65];
  const int b = blockIdx.y;
  const int n0 = blockIdx.x * 64;
  const int tid = threadIdx.x;
  const int w = tid >> 6;
  const int lane = tid & 63;

  float wv[6];
#pragma unroll
  for (int c = 0; c < 6; ++c) wv[c] = W[lane * 6 + c];
  const float scale = ss[lane];
  const float shift = ss[Edim + lane];
  const float* xb = xyz + (size_t)b * Ndim * Cdim;

  for (int s = 0; s < 16; ++s) {
    const int i = n0 + w * 16 + s;
    const float xi0 = xb[i * 3], xi1 = xb[i * 3 + 1], xi2 = xb[i * 3 + 2];
    const float hbase = wv[0] * xi0 + wv[1] * xi1 + wv[2] * xi2;
    const int* ip = idx + ((size_t)b * Ndim + i) * Kdim;
    float m = -INFINITY;
    for (int k = 0; k < Kdim; ++k) {
      const int j = ip[k];
      const float d0 = xb[j * 3] - xi0;
      const float d1 = xb[j * 3 + 1] - xi1;
      const float d2 = xb[j * 3 + 2] - xi2;
      const float h = hbase + wv[3] * d0 + wv[4] * d1 + wv[5] * d2;
      const float a = h * scale + shift;
      const float r6 = fminf(fmaxf(a + 3.0f, 0.0f), 6.0f);
      const float hs = a * r6 * (1.0f / 6.0f);
      m = fmaxf(m, hs);
    }
    sm[w * 16 + s][lane] = m;
  }
  __syncthreads();

#pragma unroll
  for (int r = 0; r < 16; ++r) {
    const int e = r * 4 + w;
    out[((size_t)b * Edim + e) * Ndim + n0 + lane] = sm[lane][e];
  }
}

// ---------------------------------------------------------------------------
extern "C" void kernel_launch(void* const* d_in, const int* in_sizes, int n_in,
                              void* d_out, int out_size, void* d_ws, size_t ws_size,
                              hipStream_t stream) {
  const float* xyz = (const float*)d_in[0];
  const float* W = (const float*)d_in[1];
  const float* gamma = (const float*)d_in[2];
  const float* beta = (const float*)d_in[3];
  float* out = (float*)d_out;

  char* ws = (char*)d_ws;
  int* idx = (int*)ws;                                        // 5,242,880 B
  float* partials = (float*)(ws + (size_t)Bdim * Ndim * Kdim * 4);  // 442,368 B
  float* ss = (float*)(ws + (size_t)Bdim * Ndim * Kdim * 4 + (size_t)NBLK1 * NPART * 4);

  // Output 0: xyz passthrough
  hipMemcpyAsync(out, xyz, (size_t)Bdim * Ndim * Cdim * sizeof(float),
                 hipMemcpyDeviceToDevice, stream);

  k1_knn_stats<<<dim3(Ndim / 16, Bdim), 256, 0, stream>>>(xyz, idx, partials);
  k2_bnstats<<<1, 256, 0, stream>>>(partials, W, gamma, beta, ss);
  k3_out<<<dim3(Ndim / 64, Bdim), 256, 0, stream>>>(
      xyz, idx, W, ss, out + (size_t)Bdim * Ndim * Cdim);
}

// Round 4
// 544.774 us; speedup vs baseline: 3.3184x; 1.4254x over previous
//
#include <hip/hip_runtime.h>
#include <math.h>

// Problem constants
#define Bdim 32
#define Ndim 2048
#define Cdim 3
#define Kdim 20
#define Edim 64
#define NPART 27                 // 6 first moments + 21 second moments
#define NBLK1 4096               // k1 grid = 128 x 32
#define CNT (Bdim * Ndim * Kdim) // BN sample count = 1,310,720

// ---------------------------------------------------------------------------
// Kernel 1: KNN top-20 per point + 27 edge-moment partial sums per block.
// One wave per point. NO per-lane key array (R2/R3 showed kd[32] spills to
// scratch at any achievable VGPR budget): each lane holds only its top-2
// (head/second) candidates + a 32-bit consumed-slot bitmask. Per round:
// 64-lane u64 butterfly max on (sortable_dist, 2047-j) -> winner pops head,
// promotes second; on a lane's 3rd+ win (rare, ~0.3/point) it recomputes its
// 32 distances from LDS, skipping consumed slots, refilling head+second.
// Distance arithmetic identical to the R1 passing kernel.
// ---------------------------------------------------------------------------
__global__ __launch_bounds__(256) void k1_knn_stats(
    const float* __restrict__ xyz, int* __restrict__ idx_out,
    float* __restrict__ partials) {
  __shared__ float4 pts[Ndim];       // {x, y, z, ||p||^2}  (32 KiB)
  __shared__ float red[4][NPART];

  const int b = blockIdx.y;
  const int tid = threadIdx.x;
  const float* xb = xyz + (size_t)b * Ndim * Cdim;

  // Stage xyz[b] into LDS
  float* sp = (float*)&pts[0];
  for (int g = tid; g < Ndim * Cdim; g += 256) {
    sp[(g / 3) * 4 + (g % 3)] = xb[g];
  }
  __syncthreads();
  for (int p = tid; p < Ndim; p += 256) {
    float4 q = pts[p];
    pts[p].w = q.x * q.x + q.y * q.y + q.z * q.z;
  }
  __syncthreads();

  const int w = tid >> 6;
  const int lane = tid & 63;
  const unsigned il = 2047u - (unsigned)lane;

  float acc[NPART];
#pragma unroll
  for (int c = 0; c < NPART; ++c) acc[c] = 0.0f;

  for (int s = 0; s < 4; ++s) {
    const int i = blockIdx.x * 16 + w * 4 + s;
    const float4 pi = pts[i];

    unsigned mask = 0u;           // bit t -> slot j = t*64+lane consumed
    unsigned hk = 0u, hlo = 0u;   // head: key + (2047-j)
    unsigned sk = 0u, slo = 0u;   // second: key + (2047-j); sk==0 -> invalid

    // Initial top-2 scan over this lane's 32 candidates (no key storage)
#pragma unroll 8
    for (int t = 0; t < 32; ++t) {
      const int j = t * 64 + lane;
      const float4 pj = pts[j];
      const float dot = pi.x * pj.x + pi.y * pj.y + pi.z * pj.z;
      const float pd = 2.0f * dot - pi.w - pj.w;   // -||pi-pj||^2
      const unsigned u = __float_as_uint(pd);
      const unsigned k = u ^ ((unsigned)(((int)u) >> 31) | 0x80000000u); // sortable, >0
      const unsigned tlo = il - (unsigned)(t * 64);
      const bool b1 = k > hk;
      const bool b2 = k > sk;
      sk  = b1 ? hk  : (b2 ? k   : sk);
      slo = b1 ? hlo : (b2 ? tlo : slo);
      hk  = b1 ? k   : hk;
      hlo = b1 ? tlo : hlo;
    }

    unsigned myJ = 0u;
    for (int r = 0; r < Kdim; ++r) {
      const unsigned long long H = ((unsigned long long)hk << 32) | hlo;
      unsigned long long best = H;
#pragma unroll
      for (int d = 1; d < 64; d <<= 1) {
        const unsigned long long o = __shfl_xor(best, d, 64);
        best = (o > best) ? o : best;
      }
      const unsigned jwin = 2047u - ((unsigned)best & 0x7FFu);
      if (lane == r) myJ = jwin;

      // Mark consumed slot (only the owning == winning lane matches)
      const bool zl = ((unsigned)lane == (jwin & 63u));
      if (zl) mask |= (1u << (jwin >> 6));

      // Winner pops: promote second, or rescan with recompute (rare)
      if (H == best) {
        if (sk != 0u) {
          hk = sk; hlo = slo; sk = 0u;
        } else {
          unsigned bk = 0u, bl = 0u, ck = 0u, cl = 0u;
          for (int t = 0; t < 32; ++t) {
            if (mask & (1u << t)) continue;
            const int j = t * 64 + lane;
            const float4 pj = pts[j];
            const float dot = pi.x * pj.x + pi.y * pj.y + pi.z * pj.z;
            const float pd = 2.0f * dot - pi.w - pj.w;
            const unsigned u = __float_as_uint(pd);
            const unsigned k = u ^ ((unsigned)(((int)u) >> 31) | 0x80000000u);
            const unsigned tlo = il - (unsigned)(t * 64);
            const bool b1 = k > bk;
            const bool b2 = k > ck;
            ck = b1 ? bk : (b2 ? k   : ck);
            cl = b1 ? bl : (b2 ? tlo : cl);
            bk = b1 ? k  : bk;
            bl = b1 ? tlo : bl;
          }
          hk = bk; hlo = bl; sk = ck; slo = cl;
        }
      }
    }

    if (lane < Kdim) {
      idx_out[((size_t)b * Ndim + i) * Kdim + lane] = (int)myJ;
      const float4 pj = pts[myJ];
      float ev[6];
      ev[0] = pi.x; ev[1] = pi.y; ev[2] = pi.z;
      ev[3] = pj.x - pi.x; ev[4] = pj.y - pi.y; ev[5] = pj.z - pi.z;
#pragma unroll
      for (int a = 0; a < 6; ++a) acc[a] += ev[a];
      int c = 6;
#pragma unroll
      for (int a = 0; a < 6; ++a)
#pragma unroll
        for (int d = a; d < 6; ++d) { acc[c] += ev[a] * ev[d]; ++c; }
    }
  }

  // Block reduction of the 27 accumulators
#pragma unroll
  for (int c = 0; c < NPART; ++c) {
    float v = acc[c];
#pragma unroll
    for (int d = 1; d < 64; d <<= 1) v += __shfl_xor(v, d, 64);
    if (lane == 0) red[w][c] = v;
  }
  __syncthreads();
  if (tid < NPART) {
    const int bid = blockIdx.y * gridDim.x + blockIdx.x;
    partials[(size_t)bid * NPART + tid] =
        red[0][tid] + red[1][tid] + red[2][tid] + red[3][tid];
  }
}

// ---------------------------------------------------------------------------
// Kernel 2: reduce 4096 partials (f64), fold 6x6 moments through W into
// per-channel BN scale/shift.
// ---------------------------------------------------------------------------
__global__ __launch_bounds__(256) void k2_bnstats(
    const float* __restrict__ partials, const float* __restrict__ W,
    const float* __restrict__ gamma, const float* __restrict__ beta,
    float* __restrict__ ss) {
  __shared__ double stat[NPART];
  __shared__ double red[4];
  const int tid = threadIdx.x;
  const int lane = tid & 63;
  const int w = tid >> 6;

  for (int c = 0; c < NPART; ++c) {
    double v = 0.0;
    for (int p = tid; p < NBLK1; p += 256) v += (double)partials[(size_t)p * NPART + c];
#pragma unroll
    for (int d = 1; d < 64; d <<= 1) v += __shfl_xor(v, d, 64);
    if (lane == 0) red[w] = v;
    __syncthreads();
    if (tid == 0) stat[c] = red[0] + red[1] + red[2] + red[3];
    __syncthreads();
  }

  if (tid < Edim) {
    const double inv = 1.0 / (double)CNT;
    double mu[6];
#pragma unroll
    for (int c = 0; c < 6; ++c) mu[c] = stat[c] * inv;
    double wv[6];
#pragma unroll
    for (int c = 0; c < 6; ++c) wv[c] = (double)W[tid * 6 + c];
    double m = 0.0;
#pragma unroll
    for (int c = 0; c < 6; ++c) m += wv[c] * mu[c];
    double q = 0.0;
    int s = 6;
#pragma unroll
    for (int a = 0; a < 6; ++a)
#pragma unroll
      for (int d = a; d < 6; ++d) {
        q += (a == d ? 1.0 : 2.0) * wv[a] * wv[d] * (stat[s] * inv);
        ++s;
      }
    const double var = q - m * m;
    const double rstd = 1.0 / sqrt(var + 1e-5);
    const float scale = (float)((double)gamma[tid] * rstd);
    const float shift = (float)((double)beta[tid] - m * rstd * (double)gamma[tid]);
    ss[tid] = scale;
    ss[Edim + tid] = shift;
  }
}

// ---------------------------------------------------------------------------
// Kernel 3: recompute h per (b,n,k,e), BN + hardswish, max over k, write
// out[b,e,n] coalesced via LDS transpose.  lane = channel e; wave = point.
// ---------------------------------------------------------------------------
__global__ __launch_bounds__(256) void k3_out(
    const float* __restrict__ xyz, const int* __restrict__ idx,
    const float* __restrict__ W, const float* __restrict__ ss,
    float* __restrict__ out) {
  __shared__ float sm[64][65];
  const int b = blockIdx.y;
  const int n0 = blockIdx.x * 64;
  const int tid = threadIdx.x;
  const int w = tid >> 6;
  const int lane = tid & 63;

  float wv[6];
#pragma unroll
  for (int c = 0; c < 6; ++c) wv[c] = W[lane * 6 + c];
  const float scale = ss[lane];
  const float shift = ss[Edim + lane];
  const float* xb = xyz + (size_t)b * Ndim * Cdim;

  for (int s = 0; s < 16; ++s) {
    const int i = n0 + w * 16 + s;
    const float xi0 = xb[i * 3], xi1 = xb[i * 3 + 1], xi2 = xb[i * 3 + 2];
    const float hbase = wv[0] * xi0 + wv[1] * xi1 + wv[2] * xi2;
    const int* ip = idx + ((size_t)b * Ndim + i) * Kdim;
    float m = -INFINITY;
    for (int k = 0; k < Kdim; ++k) {
      const int j = ip[k];
      const float d0 = xb[j * 3] - xi0;
      const float d1 = xb[j * 3 + 1] - xi1;
      const float d2 = xb[j * 3 + 2] - xi2;
      const float h = hbase + wv[3] * d0 + wv[4] * d1 + wv[5] * d2;
      const float a = h * scale + shift;
      const float r6 = fminf(fmaxf(a + 3.0f, 0.0f), 6.0f);
      const float hs = a * r6 * (1.0f / 6.0f);
      m = fmaxf(m, hs);
    }
    sm[w * 16 + s][lane] = m;
  }
  __syncthreads();

#pragma unroll
  for (int r = 0; r < 16; ++r) {
    const int e = r * 4 + w;
    out[((size_t)b * Edim + e) * Ndim + n0 + lane] = sm[lane][e];
  }
}

// ---------------------------------------------------------------------------
extern "C" void kernel_launch(void* const* d_in, const int* in_sizes, int n_in,
                              void* d_out, int out_size, void* d_ws, size_t ws_size,
                              hipStream_t stream) {
  const float* xyz = (const float*)d_in[0];
  const float* W = (const float*)d_in[1];
  const float* gamma = (const float*)d_in[2];
  const float* beta = (const float*)d_in[3];
  float* out = (float*)d_out;

  char* ws = (char*)d_ws;
  int* idx = (int*)ws;                                        // 5,242,880 B
  float* partials = (float*)(ws + (size_t)Bdim * Ndim * Kdim * 4);  // 442,368 B
  float* ss = (float*)(ws + (size_t)Bdim * Ndim * Kdim * 4 + (size_t)NBLK1 * NPART * 4);

  // Output 0: xyz passthrough
  hipMemcpyAsync(out, xyz, (size_t)Bdim * Ndim * Cdim * sizeof(float),
                 hipMemcpyDeviceToDevice, stream);

  k1_knn_stats<<<dim3(Ndim / 16, Bdim), 256, 0, stream>>>(xyz, idx, partials);
  k2_bnstats<<<1, 256, 0, stream>>>(partials, W, gamma, beta, ss);
  k3_out<<<dim3(Ndim / 64, Bdim), 256, 0, stream>>>(
      xyz, idx, W, ss, out + (size_t)Bdim * Ndim * Cdim);
}

// Round 5
// 444.343 us; speedup vs baseline: 4.0685x; 1.2260x over previous
//
#include <hip/hip_runtime.h>
#include <math.h>

// Problem constants
#define Bdim 32
#define Ndim 2048
#define Cdim 3
#define Kdim 20
#define Edim 64
#define NPART 27                 // 6 first moments + 21 second moments
#define NBLK1 4096               // k1 grid = 128 x 32
#define CNT (Bdim * Ndim * Kdim) // BN sample count = 1,310,720

// DPP controls: row_ror:N = 0x120|N, row_bcast15 = 0x142, row_bcast31 = 0x143
__device__ __forceinline__ unsigned dpp_mov(unsigned old, unsigned v, int ctrl) {
  return 0u; // never called; specialization below
}
#define DPPU(v, ctrl) \
  ((unsigned)__builtin_amdgcn_update_dpp((int)(v), (int)(v), (ctrl), 0xf, 0xf, false))
#define DPPF(v, ctrl) \
  (__int_as_float(__builtin_amdgcn_update_dpp(__float_as_int(v), __float_as_int(v), (ctrl), 0xf, 0xf, false)))

// Wave-wide max; result valid in lane 63 (rows hold row-max after ror steps).
__device__ __forceinline__ unsigned red_max_u32_l63(unsigned v) {
  unsigned t;
  t = DPPU(v, 0x121); v = (v > t) ? v : t;  // row_ror:1
  t = DPPU(v, 0x122); v = (v > t) ? v : t;  // row_ror:2
  t = DPPU(v, 0x124); v = (v > t) ? v : t;  // row_ror:4
  t = DPPU(v, 0x128); v = (v > t) ? v : t;  // row_ror:8 -> row max everywhere
  t = DPPU(v, 0x142); v = (v > t) ? v : t;  // row_bcast15
  t = DPPU(v, 0x143); v = (v > t) ? v : t;  // row_bcast31 -> lane63 global
  return v;
}

// Wave-wide sum; result valid in lane 63 only.
__device__ __forceinline__ float red_add_f32_l63(float v) {
  float t;
  t = DPPF(v, 0x121); v += t;
  t = DPPF(v, 0x122); v += t;
  t = DPPF(v, 0x124); v += t;
  t = DPPF(v, 0x128); v += t;   // row sum in every lane of the row
  t = DPPF(v, 0x142); v += t;   // lanes16-31 += lane15, 32-47 += 31, 48-63 += 47
  t = DPPF(v, 0x143); v += t;   // lanes32-63 += lane31(new) -> lane63 = total
  return v;
}

// ---------------------------------------------------------------------------
// Kernel 1: KNN top-20 per point + 27 edge-moment partial sums per block.
// One wave per point; per-lane top-2 + consumed bitmask (no key array: R2/R3
// showed kd[32] spills). Per round: DPP VALU-only max reduce on u32 keys
// (no ds_bpermute latency chain), ballot + readlane for the winner's index,
// exact smaller-index tie-break via rare uniform fallback reduce on hlo.
// ---------------------------------------------------------------------------
__global__ __launch_bounds__(256) void k1_knn_stats(
    const float* __restrict__ xyz, int* __restrict__ idx_out,
    float* __restrict__ partials) {
  __shared__ float4 pts[Ndim];       // {x, y, z, ||p||^2}  (32 KiB)
  __shared__ float red[4][NPART];

  const int b = blockIdx.y;
  const int tid = threadIdx.x;
  const float* xb = xyz + (size_t)b * Ndim * Cdim;

  // Stage xyz[b] into LDS
  float* sp = (float*)&pts[0];
  for (int g = tid; g < Ndim * Cdim; g += 256) {
    sp[(g / 3) * 4 + (g % 3)] = xb[g];
  }
  __syncthreads();
  for (int p = tid; p < Ndim; p += 256) {
    float4 q = pts[p];
    pts[p].w = q.x * q.x + q.y * q.y + q.z * q.z;
  }
  __syncthreads();

  const int w = tid >> 6;
  const int lane = tid & 63;
  const unsigned il = 2047u - (unsigned)lane;

  float acc[NPART];
#pragma unroll
  for (int c = 0; c < NPART; ++c) acc[c] = 0.0f;

  for (int s = 0; s < 4; ++s) {
    const int i = blockIdx.x * 16 + w * 4 + s;
    const float4 pi = pts[i];

    unsigned mask = 0u;           // bit t -> slot j = t*64+lane consumed
    unsigned hk = 0u, hlo = 0u;   // head: key + (2047-j)
    unsigned sk = 0u, slo = 0u;   // second; sk==0 -> invalid (real keys != 0)

#pragma unroll 8
    for (int t = 0; t < 32; ++t) {
      const int j = t * 64 + lane;
      const float4 pj = pts[j];
      const float dot = pi.x * pj.x + pi.y * pj.y + pi.z * pj.z;
      const float pd = 2.0f * dot - pi.w - pj.w;   // -||pi-pj||^2
      const unsigned u = __float_as_uint(pd);
      const unsigned k = u ^ ((unsigned)(((int)u) >> 31) | 0x80000000u); // sortable
      const unsigned tlo = il - (unsigned)(t * 64);
      const bool b1 = k > hk;
      const bool b2 = k > sk;
      sk  = b1 ? hk  : (b2 ? k   : sk);
      slo = b1 ? hlo : (b2 ? tlo : slo);
      hk  = b1 ? k   : hk;
      hlo = b1 ? tlo : hlo;
    }

    unsigned myJ = 0u;
    for (int r = 0; r < Kdim; ++r) {
      // 1) global max of heads (u32 keys), VALU-only DPP reduce
      const unsigned bm = red_max_u32_l63(hk);
      const unsigned bestk = (unsigned)__builtin_amdgcn_readlane((int)bm, 63);

      // 2) winner index: ballot of head==best; tie -> max hlo (smaller j)
      const unsigned long long mb = __ballot(hk == bestk);
      unsigned jwin;
      if ((mb & (mb - 1ull)) == 0ull) {            // single owner (common)
        const int wl = __ffsll(mb) - 1;
        jwin = 2047u - (unsigned)__builtin_amdgcn_readlane((int)hlo, wl);
      } else {                                      // exact tie (rare), uniform
        unsigned cand = (hk == bestk) ? hlo : 0u;
        cand = red_max_u32_l63(cand);
        jwin = 2047u - (unsigned)__builtin_amdgcn_readlane((int)cand, 63);
      }
      if (lane == r) myJ = jwin;

      // 3) owner lane pops: mark slot consumed, promote second or rescan
      if ((unsigned)lane == (jwin & 63u)) {
        mask |= (1u << (jwin >> 6));
        if (sk != 0u) {
          hk = sk; hlo = slo; sk = 0u;
        } else {
          unsigned bk = 0u, bl = 0u, ck = 0u, cl = 0u;
          for (int t = 0; t < 32; ++t) {
            if (mask & (1u << t)) continue;
            const int j = t * 64 + lane;
            const float4 pj = pts[j];
            const float dot = pi.x * pj.x + pi.y * pj.y + pi.z * pj.z;
            const float pd = 2.0f * dot - pi.w - pj.w;
            const unsigned u = __float_as_uint(pd);
            const unsigned k = u ^ ((unsigned)(((int)u) >> 31) | 0x80000000u);
            const unsigned tlo = il - (unsigned)(t * 64);
            const bool b1 = k > bk;
            const bool b2 = k > ck;
            ck = b1 ? bk : (b2 ? k   : ck);
            cl = b1 ? bl : (b2 ? tlo : cl);
            bk = b1 ? k  : bk;
            bl = b1 ? tlo : bl;
          }
          hk = bk; hlo = bl; sk = ck; slo = cl;
        }
      }
    }

    if (lane < Kdim) {
      idx_out[((size_t)b * Ndim + i) * Kdim + lane] = (int)myJ;
      const float4 pj = pts[myJ];
      float ev[6];
      ev[0] = pi.x; ev[1] = pi.y; ev[2] = pi.z;
      ev[3] = pj.x - pi.x; ev[4] = pj.y - pi.y; ev[5] = pj.z - pi.z;
#pragma unroll
      for (int a = 0; a < 6; ++a) acc[a] += ev[a];
      int c = 6;
#pragma unroll
      for (int a = 0; a < 6; ++a)
#pragma unroll
        for (int d = a; d < 6; ++d) { acc[c] += ev[a] * ev[d]; ++c; }
    }
  }

  // Block reduction of the 27 accumulators (DPP adds; lane63 holds wave sum)
#pragma unroll
  for (int c = 0; c < NPART; ++c) {
    const float v = red_add_f32_l63(acc[c]);
    if (lane == 63) red[w][c] = v;
  }
  __syncthreads();
  if (tid < NPART) {
    const int bid = blockIdx.y * gridDim.x + blockIdx.x;
    partials[(size_t)bid * NPART + tid] =
        red[0][tid] + red[1][tid] + red[2][tid] + red[3][tid];
  }
}

// ---------------------------------------------------------------------------
// Kernel 2: reduce 4096 partials (f64), fold 6x6 moments through W into
// per-channel BN scale/shift.
// ---------------------------------------------------------------------------
__global__ __launch_bounds__(256) void k2_bnstats(
    const float* __restrict__ partials, const float* __restrict__ W,
    const float* __restrict__ gamma, const float* __restrict__ beta,
    float* __restrict__ ss) {
  __shared__ double stat[NPART];
  __shared__ double red[4];
  const int tid = threadIdx.x;
  const int lane = tid & 63;
  const int w = tid >> 6;

  for (int c = 0; c < NPART; ++c) {
    double v = 0.0;
    for (int p = tid; p < NBLK1; p += 256) v += (double)partials[(size_t)p * NPART + c];
#pragma unroll
    for (int d = 1; d < 64; d <<= 1) v += __shfl_xor(v, d, 64);
    if (lane == 0) red[w] = v;
    __syncthreads();
    if (tid == 0) stat[c] = red[0] + red[1] + red[2] + red[3];
    __syncthreads();
  }

  if (tid < Edim) {
    const double inv = 1.0 / (double)CNT;
    double mu[6];
#pragma unroll
    for (int c = 0; c < 6; ++c) mu[c] = stat[c] * inv;
    double wv[6];
#pragma unroll
    for (int c = 0; c < 6; ++c) wv[c] = (double)W[tid * 6 + c];
    double m = 0.0;
#pragma unroll
    for (int c = 0; c < 6; ++c) m += wv[c] * mu[c];
    double q = 0.0;
    int s = 6;
#pragma unroll
    for (int a = 0; a < 6; ++a)
#pragma unroll
      for (int d = a; d < 6; ++d) {
        q += (a == d ? 1.0 : 2.0) * wv[a] * wv[d] * (stat[s] * inv);
        ++s;
      }
    const double var = q - m * m;
    const double rstd = 1.0 / sqrt(var + 1e-5);
    const float scale = (float)((double)gamma[tid] * rstd);
    const float shift = (float)((double)beta[tid] - m * rstd * (double)gamma[tid]);
    ss[tid] = scale;
    ss[Edim + tid] = shift;
  }
}

// ---------------------------------------------------------------------------
// Kernel 3: recompute h per (b,n,k,e), BN + hardswish, max over k, write
// out[b,e,n] coalesced via LDS transpose.  lane = channel e; wave = point.
// xyz[b] staged in LDS to avoid scattered global gathers.
// ---------------------------------------------------------------------------
__global__ __launch_bounds__(256) void k3_out(
    const float* __restrict__ xyz, const int* __restrict__ idx,
    const float* __restrict__ W, const float* __restrict__ ss,
    float* __restrict__ out) {
  __shared__ float4 pts[Ndim];   // 32 KiB: {x,y,z,unused}
  __shared__ float sm[64][65];
  const int b = blockIdx.y;
  const int n0 = blockIdx.x * 64;
  const int tid = threadIdx.x;
  const int w = tid >> 6;
  const int lane = tid & 63;
  const float* xb = xyz + (size_t)b * Ndim * Cdim;

  float* sp = (float*)&pts[0];
  for (int g = tid; g < Ndim * Cdim; g += 256) {
    sp[(g / 3) * 4 + (g % 3)] = xb[g];
  }
  __syncthreads();

  float wv[6];
#pragma unroll
  for (int c = 0; c < 6; ++c) wv[c] = W[lane * 6 + c];
  const float scale = ss[lane];
  const float shift = ss[Edim + lane];

  for (int s = 0; s < 16; ++s) {
    const int i = n0 + w * 16 + s;
    const float4 pi = pts[i];
    const float hbase = wv[0] * pi.x + wv[1] * pi.y + wv[2] * pi.z;
    const int* ip = idx + ((size_t)b * Ndim + i) * Kdim;
    float m = -INFINITY;
    for (int k = 0; k < Kdim; ++k) {
      const int j = ip[k];
      const float4 pj = pts[j];
      const float h = hbase + wv[3] * (pj.x - pi.x) + wv[4] * (pj.y - pi.y) +
                      wv[5] * (pj.z - pi.z);
      const float a = h * scale + shift;
      const float r6 = fminf(fmaxf(a + 3.0f, 0.0f), 6.0f);
      const float hs = a * r6 * (1.0f / 6.0f);
      m = fmaxf(m, hs);
    }
    sm[w * 16 + s][lane] = m;
  }
  __syncthreads();

#pragma unroll
  for (int r = 0; r < 16; ++r) {
    const int e = r * 4 + w;
    out[((size_t)b * Edim + e) * Ndim + n0 + lane] = sm[lane][e];
  }
}

// ---------------------------------------------------------------------------
extern "C" void kernel_launch(void* const* d_in, const int* in_sizes, int n_in,
                              void* d_out, int out_size, void* d_ws, size_t ws_size,
                              hipStream_t stream) {
  const float* xyz = (const float*)d_in[0];
  const float* W = (const float*)d_in[1];
  const float* gamma = (const float*)d_in[2];
  const float* beta = (const float*)d_in[3];
  float* out = (float*)d_out;

  char* ws = (char*)d_ws;
  int* idx = (int*)ws;                                        // 5,242,880 B
  float* partials = (float*)(ws + (size_t)Bdim * Ndim * Kdim * 4);  // 442,368 B
  float* ss = (float*)(ws + (size_t)Bdim * Ndim * Kdim * 4 + (size_t)NBLK1 * NPART * 4);

  // Output 0: xyz passthrough
  hipMemcpyAsync(out, xyz, (size_t)Bdim * Ndim * Cdim * sizeof(float),
                 hipMemcpyDeviceToDevice, stream);

  k1_knn_stats<<<dim3(Ndim / 16, Bdim), 256, 0, stream>>>(xyz, idx, partials);
  k2_bnstats<<<1, 256, 0, stream>>>(partials, W, gamma, beta, ss);
  k3_out<<<dim3(Ndim / 64, Bdim), 256, 0, stream>>>(
      xyz, idx, W, ss, out + (size_t)Bdim * Ndim * Cdim);
}

// Round 7
// 250.497 us; speedup vs baseline: 7.2168x; 1.7738x over previous
//
#include <hip/hip_runtime.h>
#include <math.h>

// Problem constants
#define Bdim 32
#define Ndim 2048
#define Cdim 3
#define Kdim 20
#define Edim 64
#define NPART 27                 // 6 first moments + 21 second moments
#define NBLK1 2048               // k1 grid = 64 x 32
#define CNT (Bdim * Ndim * Kdim) // BN sample count = 1,310,720

#define NEG_INF __int_as_float(0xFF800000)

#define DPPU(v, ctrl) \
  ((unsigned)__builtin_amdgcn_update_dpp((int)(v), (int)(v), (ctrl), 0xf, 0xf, false))
#define DPPF(v, ctrl) \
  (__int_as_float(__builtin_amdgcn_update_dpp(__float_as_int(v), __float_as_int(v), (ctrl), 0xf, 0xf, false)))

// Wave-wide max (u32); result valid in lane 63.
__device__ __forceinline__ unsigned red_max_u32_l63(unsigned v) {
  unsigned t;
  t = DPPU(v, 0x121); v = (v > t) ? v : t;  // row_ror:1
  t = DPPU(v, 0x122); v = (v > t) ? v : t;  // row_ror:2
  t = DPPU(v, 0x124); v = (v > t) ? v : t;  // row_ror:4
  t = DPPU(v, 0x128); v = (v > t) ? v : t;  // row_ror:8
  t = DPPU(v, 0x142); v = (v > t) ? v : t;  // row_bcast15
  t = DPPU(v, 0x143); v = (v > t) ? v : t;  // row_bcast31 -> lane63 global
  return v;
}

// Wave-wide max (f32, finite values + NEG_INF sentinel); result in lane 63.
__device__ __forceinline__ float red_max_f32_l63(float v) {
  float t;
  t = DPPF(v, 0x121); v = fmaxf(v, t);
  t = DPPF(v, 0x122); v = fmaxf(v, t);
  t = DPPF(v, 0x124); v = fmaxf(v, t);
  t = DPPF(v, 0x128); v = fmaxf(v, t);
  t = DPPF(v, 0x142); v = fmaxf(v, t);
  t = DPPF(v, 0x143); v = fmaxf(v, t);
  return v;
}

// Wave-wide sum; result valid in lane 63 only.
__device__ __forceinline__ float red_add_f32_l63(float v) {
  float t;
  t = DPPF(v, 0x121); v += t;
  t = DPPF(v, 0x122); v += t;
  t = DPPF(v, 0x124); v += t;
  t = DPPF(v, 0x128); v += t;
  t = DPPF(v, 0x142); v += t;
  t = DPPF(v, 0x143); v += t;
  return v;
}

__device__ __forceinline__ float sreadf(float v, int l) {
  return __int_as_float(__builtin_amdgcn_readlane(__float_as_int(v), l));
}

// ---------------------------------------------------------------------------
// Kernel 1: KNN top-20 per point + 27 edge-moment partial sums per block.
// 512 threads = 8 waves sharing one pts[] copy (33 KB -> 4 blocks/CU = 32
// waves/CU = 8 waves/SIMD). One wave per point; per-lane TOP-3 cache (float
// keys) + consumed bitmask. Per round: f32 DPP max reduce (VALU-only),
// ballot + readlane for winner; exact ties via u32 reduce on (2047-j).
// Rescan (recompute 32 dists) only on a lane's 3rd win (~0.2/point).
// !!! DISTANCE EXPRESSION IS FROZEN: `dot = pi.x*pj.x + pi.y*pj.y + pi.z*pj.z;
// pd = 2.0f*dot - pi.w - pj.w` — R6 showed any re-association (explicit fmaf,
// reordered subtraction) flips near-tie selections vs the np reference and
// fails the absmax threshold. Do not "optimize" this arithmetic.
// ---------------------------------------------------------------------------
__global__ __launch_bounds__(512) void k1_knn_stats(
    const float* __restrict__ xyz, int* __restrict__ idx_out,
    float* __restrict__ partials) {
  __shared__ float4 pts[Ndim];       // {x, y, z, ||p||^2}  (32 KiB)
  __shared__ float red[8][NPART];

  const int b = blockIdx.y;
  const int tid = threadIdx.x;
  const float* xb = xyz + (size_t)b * Ndim * Cdim;

  // Stage xyz[b] into LDS
  float* sp = (float*)&pts[0];
  for (int g = tid; g < Ndim * Cdim; g += 512) {
    sp[(g / 3) * 4 + (g % 3)] = xb[g];
  }
  __syncthreads();
  for (int p = tid; p < Ndim; p += 512) {
    float4 q = pts[p];
    pts[p].w = q.x * q.x + q.y * q.y + q.z * q.z;
  }
  __syncthreads();

  const int w = tid >> 6;
  const int lane = tid & 63;
  const unsigned il = 2047u - (unsigned)lane;

  float acc[NPART];
#pragma unroll
  for (int c = 0; c < NPART; ++c) acc[c] = 0.0f;

  for (int s = 0; s < 4; ++s) {
    const int i = blockIdx.x * 32 + w * 4 + s;
    const float4 pi = pts[i];

    unsigned mask = 0u;                   // bit t -> slot j = t*64+lane consumed
    float h1 = NEG_INF, h2 = NEG_INF, h3 = NEG_INF;
    unsigned l1 = 0u, l2 = 0u, l3 = 0u;   // 2047-j

    // Initial top-3 scan over this lane's 32 candidates
#pragma unroll 8
    for (int t = 0; t < 32; ++t) {
      const int j = t * 64 + lane;
      const float4 pj = pts[j];
      const float dot = pi.x * pj.x + pi.y * pj.y + pi.z * pj.z;
      const float pd = 2.0f * dot - pi.w - pj.w;   // -||pi-pj||^2 (FROZEN)
      const unsigned tl = il - (unsigned)(t * 64);
      const bool b1 = pd > h1;
      const bool b2 = pd > h2;
      const bool b3 = pd > h3;
      h3 = b3 ? (b2 ? h2 : pd) : h3;  l3 = b3 ? (b2 ? l2 : tl) : l3;
      h2 = b2 ? (b1 ? h1 : pd) : h2;  l2 = b2 ? (b1 ? l1 : tl) : l2;
      h1 = b1 ? pd : h1;              l1 = b1 ? tl : l1;
    }

    unsigned myJ = 0u;
    for (int r = 0; r < Kdim; ++r) {
      // 1) global max of heads (f32, exact), VALU-only DPP reduce
      const float bm = red_max_f32_l63(h1);
      const float bestk = sreadf(bm, 63);

      // 2) winner index: ballot of head==best; exact tie -> max (2047-j)
      const unsigned long long mb = __ballot(h1 == bestk);
      unsigned jwin;
      if ((mb & (mb - 1ull)) == 0ull) {            // single owner (common)
        const int wl = __ffsll((unsigned long long)mb) - 1;
        jwin = 2047u - (unsigned)__builtin_amdgcn_readlane((int)l1, wl);
      } else {                                      // exact tie (rare), uniform
        unsigned cand = (h1 == bestk) ? l1 : 0u;
        cand = red_max_u32_l63(cand);
        jwin = 2047u - (unsigned)__builtin_amdgcn_readlane((int)cand, 63);
      }
      if (lane == r) myJ = jwin;

      // 3) owner lane pops: mark consumed, promote, or rescan on 3rd win
      if ((unsigned)lane == (jwin & 63u)) {
        mask |= (1u << (jwin >> 6));
        if (h2 != NEG_INF) {
          h1 = h2; l1 = l2; h2 = h3; l2 = l3; h3 = NEG_INF;
        } else {
          float a1 = NEG_INF, a2 = NEG_INF, a3 = NEG_INF;
          unsigned c1 = 0u, c2 = 0u, c3 = 0u;
          for (int t = 0; t < 32; ++t) {
            if (mask & (1u << t)) continue;
            const int j = t * 64 + lane;
            const float4 pj = pts[j];
            const float dot = pi.x * pj.x + pi.y * pj.y + pi.z * pj.z;
            const float pd = 2.0f * dot - pi.w - pj.w;   // (FROZEN)
            const unsigned tl = il - (unsigned)(t * 64);
            const bool b1 = pd > a1;
            const bool b2 = pd > a2;
            const bool b3 = pd > a3;
            a3 = b3 ? (b2 ? a2 : pd) : a3;  c3 = b3 ? (b2 ? c2 : tl) : c3;
            a2 = b2 ? (b1 ? a1 : pd) : a2;  c2 = b2 ? (b1 ? c1 : tl) : c2;
            a1 = b1 ? pd : a1;              c1 = b1 ? tl : c1;
          }
          h1 = a1; l1 = c1; h2 = a2; l2 = c2; h3 = a3; l3 = c3;
        }
      }
    }

    if (lane < Kdim) {
      idx_out[((size_t)b * Ndim + i) * Kdim + lane] = (int)myJ;
      const float4 pj = pts[myJ];
      float ev[6];
      ev[0] = pi.x; ev[1] = pi.y; ev[2] = pi.z;
      ev[3] = pj.x - pi.x; ev[4] = pj.y - pi.y; ev[5] = pj.z - pi.z;
#pragma unroll
      for (int a = 0; a < 6; ++a) acc[a] += ev[a];
      int c = 6;
#pragma unroll
      for (int a = 0; a < 6; ++a)
#pragma unroll
        for (int d = a; d < 6; ++d) { acc[c] += ev[a] * ev[d]; ++c; }
    }
  }

  // Block reduction of the 27 accumulators (DPP adds; lane63 holds wave sum)
#pragma unroll
  for (int c = 0; c < NPART; ++c) {
    const float v = red_add_f32_l63(acc[c]);
    if (lane == 63) red[w][c] = v;
  }
  __syncthreads();
  if (tid < NPART) {
    const int bid = blockIdx.y * gridDim.x + blockIdx.x;
    float v = 0.0f;
#pragma unroll
    for (int q = 0; q < 8; ++q) v += red[q][tid];
    partials[(size_t)bid * NPART + tid] = v;
  }
}

// ---------------------------------------------------------------------------
// Kernel 2: reduce 2048 partials (f64), fold 6x6 moments through W into
// per-channel BN scale/shift.
// ---------------------------------------------------------------------------
__global__ __launch_bounds__(256) void k2_bnstats(
    const float* __restrict__ partials, const float* __restrict__ W,
    const float* __restrict__ gamma, const float* __restrict__ beta,
    float* __restrict__ ss) {
  __shared__ double stat[NPART];
  __shared__ double red[4];
  const int tid = threadIdx.x;
  const int lane = tid & 63;
  const int w = tid >> 6;

  for (int c = 0; c < NPART; ++c) {
    double v = 0.0;
    for (int p = tid; p < NBLK1; p += 256) v += (double)partials[(size_t)p * NPART + c];
#pragma unroll
    for (int d = 1; d < 64; d <<= 1) v += __shfl_xor(v, d, 64);
    if (lane == 0) red[w] = v;
    __syncthreads();
    if (tid == 0) stat[c] = red[0] + red[1] + red[2] + red[3];
    __syncthreads();
  }

  if (tid < Edim) {
    const double inv = 1.0 / (double)CNT;
    double mu[6];
#pragma unroll
    for (int c = 0; c < 6; ++c) mu[c] = stat[c] * inv;
    double wv[6];
#pragma unroll
    for (int c = 0; c < 6; ++c) wv[c] = (double)W[tid * 6 + c];
    double m = 0.0;
#pragma unroll
    for (int c = 0; c < 6; ++c) m += wv[c] * mu[c];
    double q = 0.0;
    int s = 6;
#pragma unroll
    for (int a = 0; a < 6; ++a)
#pragma unroll
      for (int d = a; d < 6; ++d) {
        q += (a == d ? 1.0 : 2.0) * wv[a] * wv[d] * (stat[s] * inv);
        ++s;
      }
    const double var = q - m * m;
    const double rstd = 1.0 / sqrt(var + 1e-5);
    const float scale = (float)((double)gamma[tid] * rstd);
    const float shift = (float)((double)beta[tid] - m * rstd * (double)gamma[tid]);
    ss[tid] = scale;
    ss[Edim + tid] = shift;
  }
}

// ---------------------------------------------------------------------------
// Kernel 3: recompute h per (b,n,k,e), BN + hardswish, max over k, write
// out[b,e,n] coalesced via LDS transpose. 512 threads; lane = channel e.
// ---------------------------------------------------------------------------
__global__ __launch_bounds__(512) void k3_out(
    const float* __restrict__ xyz, const int* __restrict__ idx,
    const float* __restrict__ W, const float* __restrict__ ss,
    float* __restrict__ out) {
  __shared__ float4 pts[Ndim];   // 32 KiB: {x,y,z,unused}
  __shared__ float sm[128][65];  // 33 KiB
  const int b = blockIdx.y;
  const int n0 = blockIdx.x * 128;
  const int tid = threadIdx.x;
  const int w = tid >> 6;
  const int lane = tid & 63;
  const float* xb = xyz + (size_t)b * Ndim * Cdim;

  float* sp = (float*)&pts[0];
  for (int g = tid; g < Ndim * Cdim; g += 512) {
    sp[(g / 3) * 4 + (g % 3)] = xb[g];
  }
  __syncthreads();

  float wv[6];
#pragma unroll
  for (int c = 0; c < 6; ++c) wv[c] = W[lane * 6 + c];
  const float scale = ss[lane];
  const float shift = ss[Edim + lane];

  for (int s = 0; s < 16; ++s) {
    const int i = n0 + w * 16 + s;
    const float4 pi = pts[i];
    const float hbase = wv[0] * pi.x + wv[1] * pi.y + wv[2] * pi.z;
    const int* ip = idx + ((size_t)b * Ndim + i) * Kdim;
    float m = -INFINITY;
    for (int k = 0; k < Kdim; ++k) {
      const int j = ip[k];
      const float4 pj = pts[j];
      const float h = hbase + wv[3] * (pj.x - pi.x) + wv[4] * (pj.y - pi.y) +
                      wv[5] * (pj.z - pi.z);
      const float a = h * scale + shift;
      const float r6 = fminf(fmaxf(a + 3.0f, 0.0f), 6.0f);
      const float hs = a * r6 * (1.0f / 6.0f);
      m = fmaxf(m, hs);
    }
    sm[w * 16 + s][lane] = m;
  }
  __syncthreads();

#pragma unroll
  for (int r = 0; r < 8; ++r) {
    const int e = r * 8 + w;
    out[((size_t)b * Edim + e) * Ndim + n0 + lane] = sm[lane][e];
    out[((size_t)b * Edim + e) * Ndim + n0 + 64 + lane] = sm[64 + lane][e];
  }
}

// ---------------------------------------------------------------------------
extern "C" void kernel_launch(void* const* d_in, const int* in_sizes, int n_in,
                              void* d_out, int out_size, void* d_ws, size_t ws_size,
                              hipStream_t stream) {
  const float* xyz = (const float*)d_in[0];
  const float* W = (const float*)d_in[1];
  const float* gamma = (const float*)d_in[2];
  const float* beta = (const float*)d_in[3];
  float* out = (float*)d_out;

  char* ws = (char*)d_ws;
  int* idx = (int*)ws;                                        // 5,242,880 B
  float* partials = (float*)(ws + (size_t)Bdim * Ndim * Kdim * 4);
  float* ss = (float*)(ws + (size_t)Bdim * Ndim * Kdim * 4 + (size_t)NBLK1 * NPART * 4);

  // Output 0: xyz passthrough
  hipMemcpyAsync(out, xyz, (size_t)Bdim * Ndim * Cdim * sizeof(float),
                 hipMemcpyDeviceToDevice, stream);

  k1_knn_stats<<<dim3(Ndim / 32, Bdim), 512, 0, stream>>>(xyz, idx, partials);
  k2_bnstats<<<1, 256, 0, stream>>>(partials, W, gamma, beta, ss);
  k3_out<<<dim3(Ndim / 128, Bdim), 512, 0, stream>>>(
      xyz, idx, W, ss, out + (size_t)Bdim * Ndim * Cdim);
}